// Round 2
// baseline (93.707 us; speedup 1.0000x reference)
//
#include <hip/hip_runtime.h>
#include <math.h>

// ADC activation: out = 0.05 * searchsorted(adc_char, clamp(x,0,7.9375), 'right') / 16
// x: 51,380,224 fp32; adc_char: 127 sorted fp32 thresholds.
// Memory-bound target: 822 MB total traffic -> ~60 us at ~7 TB/s.
//
// Strategy: bucketized lookup. idx = (int)(a*128.0f) is EXACT (mul by 2^7 is an
// exponent shift, no rounding) and monotone, so bucketing values and thresholds
// with the same expression is exactly consistent with the sorted-search.
// Bucket entry (8B, one ds_read_b64): { lo | hi<<8, first threshold in bucket (or +INF) }.
//   cnt = lo + (t0 <= a)  covers buckets with <=1 threshold (~99.3% of lookups);
//   rare >=2-threshold buckets take a short loop over the flat threshold array.
// This replaces R1's 7-deep dependent LDS binary-search chain (63% LDS-pipe busy)
// with a single LDS round per element.

#define N_LEVELS 127
#define CLAMP_MAX 7.9375f
#define OUT_SCALE 0.003125f  // 0.05 / 2^4 exactly (exponent shift of fl(0.05f))
#define NBUCKETS 1024        // idx = (int)(a*128) <= 1016

__device__ __forceinline__ float adc_eval(const float2* __restrict__ table,
                                          const float* __restrict__ th,
                                          float x) {
    float a = fminf(fmaxf(x, 0.0f), CLAMP_MAX);
    int idx = (int)(a * 128.0f);          // exact: *2^7
    float2 e = table[idx];                // ds_read_b64
    int meta = __float_as_int(e.x);
    int lo = meta & 0xFF;
    int hi = meta >> 8;
    int cnt = lo + (e.y <= a ? 1 : 0);    // e.y = +INF if bucket empty
    if (hi > lo + 1) {                    // rare: bucket holds >=2 thresholds
        for (int j = lo + 1; j < hi; ++j) cnt += (th[j] <= a ? 1 : 0);
    }
    return OUT_SCALE * (float)cnt;
}

__global__ __launch_bounds__(256) void ADCActivation_55465207660703_kernel(
        const float* __restrict__ x,
        const float* __restrict__ adc_char,
        float* __restrict__ out,
        int n4, int rem) {
    __shared__ float  th[128];            // thresholds + INF pad at [127]
    __shared__ int    bk[128];            // bucket index of each threshold
    __shared__ float2 table[NBUCKETS];    // {lo|hi<<8 (bitcast), t0 or +INF}

    const int tid = threadIdx.x;

    if (tid < N_LEVELS) {
        float t = adc_char[tid];
        th[tid] = t;
        bk[tid] = (int)(t * 128.0f);      // same exact expression as lookups
    }
    if (tid == N_LEVELS) th[tid] = INFINITY;
    __syncthreads();

    // Each thread builds 4 buckets: lo = #thresholds in earlier buckets,
    // hi = #thresholds in earlier-or-this bucket. One-time ~1k cycles.
    {
        const int b0 = tid, b1 = tid + 256, b2 = tid + 512, b3 = tid + 768;
        int lo0 = 0, hi0 = 0, lo1 = 0, hi1 = 0, lo2 = 0, hi2 = 0, lo3 = 0, hi3 = 0;
        for (int j = 0; j < N_LEVELS; ++j) {
            int bj = bk[j];               // uniform across lanes -> broadcast
            lo0 += (bj < b0); hi0 += (bj <= b0);
            lo1 += (bj < b1); hi1 += (bj <= b1);
            lo2 += (bj < b2); hi2 += (bj <= b2);
            lo3 += (bj < b3); hi3 += (bj <= b3);
        }
        table[b0] = make_float2(__int_as_float(lo0 | (hi0 << 8)), th[lo0 < hi0 ? lo0 : 127]);
        table[b1] = make_float2(__int_as_float(lo1 | (hi1 << 8)), th[lo1 < hi1 ? lo1 : 127]);
        table[b2] = make_float2(__int_as_float(lo2 | (hi2 << 8)), th[lo2 < hi2 ? lo2 : 127]);
        table[b3] = make_float2(__int_as_float(lo3 | (hi3 << 8)), th[lo3 < hi3 ? lo3 : 127]);
    }
    __syncthreads();

    const float4* __restrict__ x4 = (const float4*)x;
    float4* __restrict__ o4 = (float4*)out;

    // 2x-unrolled grid-stride: two wave-contiguous float4 loads in flight per iter.
    const int stride = gridDim.x * 512;
    for (int i0 = blockIdx.x * 512 + tid; i0 < n4; i0 += stride) {
        const int i1 = i0 + 256;
        const bool p1 = i1 < n4;          // wave-uniform (n4 % 256 == 0 here)
        float4 v0 = x4[i0];
        float4 v1 = make_float4(0.f, 0.f, 0.f, 0.f);
        if (p1) v1 = x4[i1];

        float4 r0, r1;
        r0.x = adc_eval(table, th, v0.x);
        r0.y = adc_eval(table, th, v0.y);
        r0.z = adc_eval(table, th, v0.z);
        r0.w = adc_eval(table, th, v0.w);
        r1.x = adc_eval(table, th, v1.x);
        r1.y = adc_eval(table, th, v1.y);
        r1.z = adc_eval(table, th, v1.z);
        r1.w = adc_eval(table, th, v1.w);

        o4[i0] = r0;
        if (p1) o4[i1] = r1;
    }

    // Tail (n % 4 != 0) — not hit for this problem but safe.
    if (blockIdx.x == 0 && tid < rem) {
        int e = n4 * 4 + tid;
        out[e] = adc_eval(table, th, x[e]);
    }
}

extern "C" void kernel_launch(void* const* d_in, const int* in_sizes, int n_in,
                              void* d_out, int out_size, void* d_ws, size_t ws_size,
                              hipStream_t stream) {
    const float* x        = (const float*)d_in[0];
    const float* adc_char = (const float*)d_in[1];
    float* out            = (float*)d_out;

    const int n   = in_sizes[0];
    const int n4  = n >> 2;
    const int rem = n & 3;

    int blocks = (n4 + 511) / 512;
    if (blocks > 2048) blocks = 2048;
    if (blocks < 1) blocks = 1;

    ADCActivation_55465207660703_kernel<<<blocks, 256, 0, stream>>>(x, adc_char, out, n4, rem);
}

// Round 3
// 91.199 us; speedup vs baseline: 1.0275x; 1.0275x over previous
//
#include <hip/hip_runtime.h>
#include <math.h>

// ADC activation: out = 0.05 * searchsorted(adc_char, clamp(x,0,7.9375), 'right') / 16
// x: 51,380,224 fp32; adc_char: 127 sorted fp32 thresholds.
// Memory-bound target: 411 MB true traffic -> ~65 us at ~6.3 TB/s.
//
// Bucketized lookup, branchless for buckets holding <=3 thresholds:
//   idx = (int)(a*128.0f) is EXACT (x2^7 = exponent shift) and monotone, so
//   bucketing values and thresholds with the same expression is exactly
//   consistent with the sorted search.
//   Bucket entry (16B, one ds_read_b128): { lo|hi<<8, t0, t1, t2 } where
//   tk = th[lo+k] if lo+k<hi else +INF.  cnt = lo + (t0<=a)+(t1<=a)+(t2<=a).
// Buckets with >=4 thresholds (expected ~0.01 for 127 thresholds over 1017
// buckets) are handled by a correctness fallback guarded by a BLOCK-UNIFORM
// flag hoisted to SGPR -> scalar branch, never taken at runtime, zero
// exec-mask churn.  (R2's per-lane fallback branch was taken by ~60% of
// wave-evals -> 43% VALUBusy and 119us; this removes it.)

#define N_LEVELS 127
#define CLAMP_MAX 7.9375f
#define OUT_SCALE 0.003125f  // 0.05 / 2^4 exactly (exponent shift of fl(0.05f))
#define NBUCKETS 1024        // idx = (int)(a*128) <= 1016

__device__ __forceinline__ float adc_eval(const float4* __restrict__ table,
                                          const float* __restrict__ th,
                                          int deep, float x) {
    float a = fminf(fmaxf(x, 0.0f), CLAMP_MAX);
    int idx = (int)(a * 128.0f);          // exact: *2^7, trunc==floor (a>=0)
    float4 e = table[idx];                // one ds_read_b128
    int meta = __float_as_int(e.x);
    int lo = meta & 0xFF;
    int cnt = lo + (e.y <= a ? 1 : 0) + (e.z <= a ? 1 : 0) + (e.w <= a ? 1 : 0);
    if (deep) {                           // SGPR-uniform: scalar branch, ~never taken
        int hi = meta >> 8;
        for (int j = lo + 3; j < hi; ++j) cnt += (th[j] <= a ? 1 : 0);
    }
    return OUT_SCALE * (float)cnt;
}

__global__ __launch_bounds__(256) void ADCActivation_55465207660703_kernel(
        const float* __restrict__ x,
        const float* __restrict__ adc_char,
        float* __restrict__ out,
        int n4, int rem) {
    __shared__ float  th[128];            // thresholds + INF pad at [127]
    __shared__ int    bk[128];            // bucket index of each threshold
    __shared__ float4 table[NBUCKETS];    // 16 KB
    __shared__ int    deep_s;

    const int tid = threadIdx.x;

    if (tid == 0) deep_s = 0;
    if (tid < N_LEVELS) {
        float t = adc_char[tid];
        th[tid] = t;
        bk[tid] = (int)(t * 128.0f);      // same exact expression as lookups
    }
    if (tid == N_LEVELS) th[tid] = INFINITY;
    __syncthreads();

    // Each thread builds 4 buckets. lo = #thresholds in earlier buckets,
    // hi = #thresholds in earlier-or-this bucket. One-time ~1k cycles.
    {
        const int b0 = tid, b1 = tid + 256, b2 = tid + 512, b3 = tid + 768;
        int lo0 = 0, hi0 = 0, lo1 = 0, hi1 = 0, lo2 = 0, hi2 = 0, lo3 = 0, hi3 = 0;
        for (int j = 0; j < N_LEVELS; ++j) {
            int bj = bk[j];               // uniform across lanes -> broadcast
            lo0 += (bj < b0); hi0 += (bj <= b0);
            lo1 += (bj < b1); hi1 += (bj <= b1);
            lo2 += (bj < b2); hi2 += (bj <= b2);
            lo3 += (bj < b3); hi3 += (bj <= b3);
        }
        #define MK_ENTRY(B, LO, HI)                                              \
        {                                                                        \
            int i0 = (LO + 0 < HI) ? LO + 0 : 127;                               \
            int i1 = (LO + 1 < HI) ? LO + 1 : 127;                               \
            int i2 = (LO + 2 < HI) ? LO + 2 : 127;                               \
            table[B] = make_float4(__int_as_float(LO | (HI << 8)),               \
                                   th[i0], th[i1], th[i2]);                      \
            if (HI - LO > 3) atomicOr(&deep_s, 1);                               \
        }
        MK_ENTRY(b0, lo0, hi0)
        MK_ENTRY(b1, lo1, hi1)
        MK_ENTRY(b2, lo2, hi2)
        MK_ENTRY(b3, lo3, hi3)
        #undef MK_ENTRY
    }
    __syncthreads();

    // Block-uniform by construction; force into SGPR so the fallback guard
    // compiles to a scalar branch (no per-lane exec-mask manipulation).
    const int deep = __builtin_amdgcn_readfirstlane(deep_s);

    const float4* __restrict__ x4 = (const float4*)x;
    float4* __restrict__ o4 = (float4*)out;

    // 2x-unrolled grid-stride: two wave-contiguous float4 loads in flight.
    const int stride = gridDim.x * 512;
    for (int i0 = blockIdx.x * 512 + tid; i0 < n4; i0 += stride) {
        const int i1 = i0 + 256;
        const bool p1 = i1 < n4;
        float4 v0 = x4[i0];
        float4 v1 = make_float4(0.f, 0.f, 0.f, 0.f);
        if (p1) v1 = x4[i1];

        float4 r0, r1;
        r0.x = adc_eval(table, th, deep, v0.x);
        r0.y = adc_eval(table, th, deep, v0.y);
        r0.z = adc_eval(table, th, deep, v0.z);
        r0.w = adc_eval(table, th, deep, v0.w);
        r1.x = adc_eval(table, th, deep, v1.x);
        r1.y = adc_eval(table, th, deep, v1.y);
        r1.z = adc_eval(table, th, deep, v1.z);
        r1.w = adc_eval(table, th, deep, v1.w);

        o4[i0] = r0;
        if (p1) o4[i1] = r1;
    }

    // Tail (n % 4 != 0) — not hit for this problem but safe.
    if (blockIdx.x == 0 && tid < rem) {
        int e = n4 * 4 + tid;
        out[e] = adc_eval(table, th, deep, x[e]);
    }
}

extern "C" void kernel_launch(void* const* d_in, const int* in_sizes, int n_in,
                              void* d_out, int out_size, void* d_ws, size_t ws_size,
                              hipStream_t stream) {
    const float* x        = (const float*)d_in[0];
    const float* adc_char = (const float*)d_in[1];
    float* out            = (float*)d_out;

    const int n   = in_sizes[0];
    const int n4  = n >> 2;
    const int rem = n & 3;

    int blocks = (n4 + 511) / 512;
    if (blocks > 2048) blocks = 2048;
    if (blocks < 1) blocks = 1;

    ADCActivation_55465207660703_kernel<<<blocks, 256, 0, stream>>>(x, adc_char, out, n4, rem);
}